// Round 12
// baseline (348.317 us; speedup 1.0000x reference)
//
#include <hip/hip_runtime.h>

#define NB 8
#define NN 2048
#define NF 256

typedef __attribute__((ext_vector_type(8))) short bf16x8;
typedef __attribute__((ext_vector_type(4))) float f32x4;
typedef __attribute__((ext_vector_type(4))) int i32x4;

// Fragment-ordered panel layout ("frag order"):
//   blob[kb][f][g][j]  (shorts)  kb=k/32, g=lane>>4 (k-octet), j=k&7
//   addr_sh = kb*8192 + f*32 + g*8 + j
// A wave's MFMA B-fragment load (rows f..f+15, k-octet per lane-quad) is then
// ONE contiguous 1KB load. The old [f][k] layout made every fragment load a
// 16-segment gather (~16x VMEM transaction slots) — proven R9: 176->124 us.

__device__ __forceinline__ unsigned short f2bf(float x) {
  union { float f; unsigned int i; } c; c.f = x;
  unsigned int r = c.i + 0x7FFFu + ((c.i >> 16) & 1u);
  return (unsigned short)(r >> 16);
}
// round-half-up bf16 (1 add + 1 shift) — hot convert paths
__device__ __forceinline__ unsigned short f2bf_fast(float x) {
  union { float f; unsigned int i; } c; c.f = x;
  return (unsigned short)((c.i + 0x8000u) >> 16);
}
__device__ __forceinline__ bf16x8 cvt8(float4 c0, float4 c1) {
  union { bf16x8 v8; unsigned short us[8]; } cu;
  cu.us[0] = f2bf_fast(c0.x); cu.us[1] = f2bf_fast(c0.y);
  cu.us[2] = f2bf_fast(c0.z); cu.us[3] = f2bf_fast(c0.w);
  cu.us[4] = f2bf_fast(c1.x); cu.us[5] = f2bf_fast(c1.y);
  cu.us[6] = f2bf_fast(c1.z); cu.us[7] = f2bf_fast(c1.w);
  return cu.v8;
}

// ---------------------------------------------------------------------------
// k_prep: WTr_frag[k/32][f][g][j] = bf16(W[k][f]);  u = W@a1, v = W@a2 (fp32)
// ---------------------------------------------------------------------------
__global__ __launch_bounds__(256) void k_prep(
    const float* __restrict__ W, const float* __restrict__ a,
    unsigned short* __restrict__ WT, float* __restrict__ u, float* __restrict__ v) {
  int t = threadIdx.x;
  if (blockIdx.x < 256) {
    int k = blockIdx.x;
    // frag-order: kb=k>>5, f=t, g=(k>>3)&3, j=k&7
    WT[(k >> 5) * 8192 + t * 32 + ((k >> 3) & 3) * 8 + (k & 7)] = f2bf(W[k * 256 + t]);
  } else {
    float su = 0.f, sv = 0.f;
    for (int o = 0; o < 256; ++o) {
      float w = W[t * 256 + o];
      su += w * a[o];
      sv += w * a[256 + o];
    }
    u[t] = su; v[t] = sv;
  }
}

// ---------------------------------------------------------------------------
// k_mid: WhT_frag = W^T h^T (frag-order) AND Wh1/Wh2 = h.u / h.v, one h pass.
// (R11 version, passed; h staged coalesced through 8KB swizzled LDS.)
// grid 1024: b(8) x itile(128,16 rows); 256 thr / 4 waves; LDS 8 KB.
// ---------------------------------------------------------------------------
__global__ __launch_bounds__(256) void k_mid(
    const float* __restrict__ h, const unsigned short* __restrict__ WTr,
    const float* __restrict__ u, const float* __restrict__ v,
    unsigned short* __restrict__ WhT, float* __restrict__ Wh1, float* __restrict__ Wh2) {
  __shared__ __align__(16) unsigned short sh[16 * 256];  // 8 KB bf16, swizzled
  int bx = blockIdx.x;
  int b = bx >> 7;
  int iW = (bx & 127) * 16;
  int wave = threadIdx.x >> 6, lane = threadIdx.x & 63;
  const float* hB = h + (size_t)b * NN * NF;

  // ---- stage 16 rows coalesced + fp32 u/v partials ----
  float pu[4], pw[4];
  {
    int c4 = lane * 4;                      // this lane's 4 columns
    const float* uc = u + c4;
    const float* vc = v + c4;
#pragma unroll
    for (int it = 0; it < 4; ++it) {
      int r = wave * 4 + it;                // local row 0..15
      const float* p = hB + (size_t)(iW + r) * NF + c4;
      float4 hv = *(const float4*)p;
      pu[it] = hv.x*uc[0] + hv.y*uc[1] + hv.z*uc[2] + hv.w*uc[3];
      pw[it] = hv.x*vc[0] + hv.y*vc[1] + hv.z*vc[2] + hv.w*vc[3];
      int byte = r * 512 + ((c4 * 2) ^ ((r & 7) << 4));
      union { short4 v4; unsigned short us[4]; } pk;
      pk.us[0] = f2bf_fast(hv.x); pk.us[1] = f2bf_fast(hv.y);
      pk.us[2] = f2bf_fast(hv.z); pk.us[3] = f2bf_fast(hv.w);
      *(short4*)((char*)sh + byte) = pk.v4;
    }
  }
#pragma unroll
  for (int it = 0; it < 4; ++it)
#pragma unroll
    for (int off = 32; off >= 1; off >>= 1) {
      pu[it] += __shfl_xor(pu[it], off);
      pw[it] += __shfl_xor(pw[it], off);
    }
  if (lane == 0) {
#pragma unroll
    for (int it = 0; it < 4; ++it) {
      int row = b * NN + iW + wave * 4 + it;
      Wh1[row] = pu[it];
      Wh2[row] = pw[it];
    }
  }
  __syncthreads();

  // ---- MFMA: A = WTr frag-order (global, coalesced), B = h tile from LDS ----
  int fW = wave * 64;
  int l15 = lane & 15, gq = lane >> 4, q8 = gq * 8;
  const unsigned short* wf = WTr + (fW + l15) * 32 + gq * 8;

  f32x4 acc[4];
#pragma unroll
  for (int ft = 0; ft < 4; ++ft) acc[ft] = (f32x4){0.f, 0.f, 0.f, 0.f};

  for (int k0 = 0; k0 < NF; k0 += 32) {
    int byte = l15 * 512 + ((((k0 + q8) * 2)) ^ ((l15 & 7) << 4));
    bf16x8 bfr = *(const bf16x8*)((const char*)sh + byte);
    const unsigned short* wk = wf + (k0 >> 5) * 8192;
#pragma unroll
    for (int ft = 0; ft < 4; ++ft) {
      bf16x8 af = *(const bf16x8*)(wk + ft * 512);   // 16 rows x 32 sh
      acc[ft] = __builtin_amdgcn_mfma_f32_16x16x32_bf16(af, bfr, acc[ft], 0, 0, 0);
    }
  }

  // frag-order WhT write: k-dim of phase2 is i here (unchanged from R9).
  unsigned short* WhTb = WhT + (size_t)b * NF * NN;
  int kb = iW >> 5;
  int gg = ((iW & 16) + l15) >> 3;
  int jj = l15 & 7;
  int q4 = gq * 4;
#pragma unroll
  for (int ft = 0; ft < 4; ++ft)
#pragma unroll
    for (int r = 0; r < 4; ++r) {
      int f = fW + ft * 16 + q4 + r;
      WhTb[kb * 8192 + f * 32 + gg * 8 + jj] = f2bf(acc[ft][r]);
    }
}

// ---------------------------------------------------------------------------
// k_fuse: softmax (16 rows) + att@WhT + h+elu epilogue, one block per row-tile.
// R12: 1024-thread blocks (16 waves). LDS is still 64 KB -> 2 blocks/CU, but
// now 2 x 16 = 32 waves/CU = the hardware max (was 16). Phase 1 = ONE row per
// wave (lower VGPR pressure than the proven 2-row loop); phase 2 = one 16-wide
// f-stripe per wave (single acc, one 1KB frag-order B load + 1 MFMA per
// k-step). __launch_bounds__(1024,8) pins <=64 VGPR (8 waves/SIMD).
// Rationale: phase 1 does k_soft's streaming work; standalone k_soft hit
// ~3.9 TB/s at full occupancy while fused phase 1 runs at half the waves.
// Keeps: frag-order B (R9), XCD-affine swizzle, nt on zero-reuse streams.
// grid 1024: b(8) x itile(128,16i); 1024 thr / 16 waves; LDS 64 KB.
// ---------------------------------------------------------------------------
__global__ __launch_bounds__(1024, 8) void k_fuse(
    const int* __restrict__ adj, const float* __restrict__ Wh1,
    const float* __restrict__ Wh2, const unsigned short* __restrict__ WhT,
    const float* __restrict__ h, float* __restrict__ att, float* __restrict__ out) {
  __shared__ unsigned short satt[16 * 2048];  // 64 KB, XOR-swizzled rows
  const float NEGBIG = -9.0e15f;
  int bx = blockIdx.x;
  bx = (bx & 7) * 128 + (bx >> 3);   // XCD-affine remap (bijective on [0,1024))
  int b = bx >> 7;
  int i0 = (bx & 127) * 16;
  int wave = threadIdx.x >> 6, lane = threadIdx.x & 63;
  const float* w2 = Wh2 + ((size_t)b << 11);

  // ---------------- phase 1: masked-softmax, ONE row per wave --------------
  {
    int row = b * NN + i0 + wave;
    const int* arow = adj + (size_t)row * NN;
    float w1 = Wh1[row];
    float x[32];
#pragma unroll
    for (int c = 0; c < 8; ++c) {
      int j = c * 256 + lane * 4;
      i32x4 av = __builtin_nontemporal_load((const i32x4*)(arow + j));
      float4 pv = *(const float4*)(w2 + j);
      float t;
      t = w1 + pv.x; t = t >= 0.f ? t : 0.2f * t; x[c*4+0] = (av.x > 0) ? t : NEGBIG;
      t = w1 + pv.y; t = t >= 0.f ? t : 0.2f * t; x[c*4+1] = (av.y > 0) ? t : NEGBIG;
      t = w1 + pv.z; t = t >= 0.f ? t : 0.2f * t; x[c*4+2] = (av.z > 0) ? t : NEGBIG;
      t = w1 + pv.w; t = t >= 0.f ? t : 0.2f * t; x[c*4+3] = (av.w > 0) ? t : NEGBIG;
    }

    float m = x[0];
#pragma unroll
    for (int k = 1; k < 32; ++k) m = fmaxf(m, x[k]);
#pragma unroll
    for (int off = 32; off >= 1; off >>= 1) m = fmaxf(m, __shfl_xor(m, off));
    float sum = 0.f;
#pragma unroll
    for (int k = 0; k < 32; ++k) { x[k] = __expf(x[k] - m); sum += x[k]; }
#pragma unroll
    for (int off = 32; off >= 1; off >>= 1) sum += __shfl_xor(sum, off);
    float iv = 1.0f / sum;

    int swz = wave * 8;
    float* orow = att + (size_t)row * NN;
    unsigned short* srow = satt + wave * 2048;
#pragma unroll
    for (int c = 0; c < 8; ++c) {
      int j = c * 256 + lane * 4;
      float a0 = x[c*4+0] * iv, a1 = x[c*4+1] * iv;
      float a2 = x[c*4+2] * iv, a3 = x[c*4+3] * iv;
      f32x4 ov = (f32x4){a0, a1, a2, a3};
      __builtin_nontemporal_store(ov, (f32x4*)(orow + j));
      // LDS: 4 bf16 (8B) at swizzled offset; groups of 8 permuted by swz
      int e = ((j & ~7) ^ swz) + (j & 7);
      union { short4 v4; unsigned short us[4]; } pk;
      pk.us[0] = f2bf_fast(a0); pk.us[1] = f2bf_fast(a1);
      pk.us[2] = f2bf_fast(a2); pk.us[3] = f2bf_fast(a3);
      *(short4*)(srow + e) = pk.v4;
    }
  }

  __syncthreads();

  // ---------------- phase 2: h_prime = att @ Wh, out = h + elu -------------
  int fW = wave * 16;                      // 16 waves x 16 f = 256 f
  int l15 = lane & 15, gq = lane >> 4, q8 = gq * 8;
  const unsigned short* WTb = WhT + (size_t)b * NF * NN;
  const unsigned short* aRow = satt + l15 * 2048;
  int swzA = l15 * 8;
  // frag-order B base: rows fW+l15, k-octet gq, tile kk>>5
  const unsigned short* bbase = WTb + (fW + l15) * 32 + gq * 8;

  f32x4 acc = (f32x4){0.f, 0.f, 0.f, 0.f};

#pragma unroll 4
  for (int kk = 0; kk < NN; kk += 32) {
    bf16x8 afr = *(const bf16x8*)(aRow + (((kk + q8) ^ swzA)));
    bf16x8 bfr = *(const bf16x8*)(bbase + (kk >> 5) * 8192);
    acc = __builtin_amdgcn_mfma_f32_16x16x32_bf16(afr, bfr, acc, 0, 0, 0);
  }

  int q4 = gq * 4;
#pragma unroll
  for (int r = 0; r < 4; ++r) {
    int i = i0 + q4 + r;
    int f = fW + l15;
    size_t idx = ((size_t)(b * NN + i)) * NF + f;
    float hp = acc[r];
    float el = hp > 0.f ? hp : expm1f(hp);
    float hv = __builtin_nontemporal_load(h + idx);
    __builtin_nontemporal_store(hv + el, out + idx);
  }
}

// ---------------------------------------------------------------------------
extern "C" void kernel_launch(void* const* d_in, const int* in_sizes, int n_in,
                              void* d_out, int out_size, void* d_ws, size_t ws_size,
                              hipStream_t stream) {
  // identify inputs by element count (all four are distinct)
  const float* h = nullptr; const int* adj = nullptr;
  const float* W = nullptr; const float* a = nullptr;
  for (int i = 0; i < n_in; ++i) {
    int s = in_sizes[i];
    if (s == NB * NN * NF) h = (const float*)d_in[i];
    else if (s == NB * NN * NN) adj = (const int*)d_in[i];
    else if (s == NF * NF) W = (const float*)d_in[i];
    else if (s == 2 * NF) a = (const float*)d_in[i];
  }

  float* out = (float*)d_out;                              // [8,2048,256] fp32
  float* att = out + (size_t)NB * NN * NF;                 // [8,2048,2048] fp32

  // ws footprint ~8.26 MB (proven safe; layouts reordered, sizes unchanged)
  char* ws = (char*)d_ws;
  unsigned short* WhT = (unsigned short*)ws;               // 8 MB frag-order [8][64][256][4][8]
  unsigned short* WTr = (unsigned short*)(ws + 8388608);   // 128 KB frag-order [8][256][4][8]
  float* u   = (float*)(ws + 8388608 + 131072);            // 1 KB
  float* v   = u + 256;                                    // 1 KB
  float* Wh1 = v + 256;                                    // 64 KB
  float* Wh2 = Wh1 + NB * NN;                              // 64 KB

  k_prep<<<257, 256, 0, stream>>>(W, a, WTr, u, v);
  k_mid<<<1024, 256, 0, stream>>>(h, WTr, u, v, WhT, Wh1, Wh2);
  k_fuse<<<NB * 128, 1024, 0, stream>>>(adj, Wh1, Wh2, WhT, h, att, out);
}